// Round 11
// baseline (43.368 us; speedup 1.0000x reference)
//
#include <hip/hip_runtime.h>
#include <math.h>

// Problem constants (from reference): B=128, C=3, H=256, W=256, fp32.
#define BATCH 128
#define CHAN  3
#define IMH   256
#define IMW   256
#define NXCD  8
#define TW    32   // output tile width (per block)
#define TH    16   // output half-tile height; block does TWO halves (32x32)

// Packed-RGB LDS tile: [row][col*3 + ch]. 42 rows x 44 cols x 3 ch.
// Row stride 132 dwords; 42*132*4 = 22,176 B -> 7 blocks/CU.
// One base address serves all 6 tap-pairs of a pixel (immediate offsets
// 0..5 and 132..137) and all 6 stager stores (offsets 0..5).
#define BH_T   42
#define NC_MAX 44
#define ROWSTR 132   // NC_MAX * 3

// ---------------------------------------------------------------------------
// Single fused kernel. Block = 256 threads = one 32x32 output region,
// processed as two sequential 32x16 half-tiles reusing one LDS buffer
// (halves the block count -> uniform prologue + launch overhead amortize 2x).
// Within a half: 2 px per thread stacked in h; input footprint staged in
// packed-RGB LDS; per-image affine params via HW trig (__cosf/__sinf).
// ---------------------------------------------------------------------------
__global__ __launch_bounds__(256) void affine_sample_kernel(
        const float* __restrict__ img,
        const float* __restrict__ rot,
        const float* __restrict__ trans,
        const float* __restrict__ scale,
        const float* __restrict__ shear,
        float* __restrict__ out) {
    __shared__ float tile[BH_T * ROWSTR];   // 22,176 B

    const int NBLK = BATCH * 64;           // 128 images * 64 (32x32) blocks
    const int p = blockIdx.x;
    const int L = (p & (NXCD - 1)) * (NBLK / NXCD) + (p >> 3);  // XCD-chunked

    const int b  = L >> 6;            // 64 blocks per image
    const int tl = L & 63;
    const int w0 = (tl & 7) * TW;
    const int h0 = (tl >> 3) * (2 * TH);

    // --- per-image params, block-uniform; HW trig --------------------------
    const float r   = rot[b];
    const float s   = scale[b];
    const float shx = shear[2 * b + 0];
    const float shy = shear[2 * b + 1];
    const float txr = trans[2 * b + 0];
    const float tyr = trans[2 * b + 1];
    const float c  = __cosf(r);       // v_cos_f32 (~1e-6 abs err vs 2e-2 tol)
    const float sn = __sinf(r);
    const float a00 = s * (c - sn * shy);
    const float a01 = s * (c * shx - sn);
    const float a10 = s * (sn + c * shy);
    const float a11 = s * (sn * shx + c);
    // linearized: ix(w,h) = Cx + a00*w + a01*h (exact; map is affine in w,h)
    const float g0x = 1.0f / (float)IMW - 1.0f;   // gx at w=0
    const float g0y = 1.0f / (float)IMH - 1.0f;   // gy at h=0
    const float Cx = ((a00 * g0x + a01 * g0y + txr + 1.0f) * (float)IMW - 1.0f) * 0.5f;
    const float Cy = ((a10 * g0x + a11 * g0y + tyr + 1.0f) * (float)IMH - 1.0f) * 0.5f;
    const float hx = 15.5f * fabsf(a00) + 7.5f * fabsf(a01);
    const float hy = 15.5f * fabsf(a10) + 7.5f * fabsf(a11);

    // --- per-thread invariants ---------------------------------------------
    const int t  = threadIdx.x;
    const int wq = w0 + (t & 31);
    const int hoff = (t >> 5) << 1;           // 0,2,..,14 within half-tile
    const int lx2 = (t & 31) << 1;            // stager col pair 0,2,..,62
    const int lyr = t >> 5;                   // stager row 0..7 per round
    const int plane = IMH * IMW;
    const float* ibase = img + (size_t)(b * CHAN) * plane;

    for (int half = 0; half < 2; ++half) {
        const int h0h = h0 + half * TH;

        // --- block-uniform bbox of this half's input footprint -------------
        const float ixc = Cx + a00 * ((float)w0 + 15.5f) + a01 * ((float)h0h + 7.5f);
        const float iyc = Cy + a10 * ((float)w0 + 15.5f) + a11 * ((float)h0h + 7.5f);
        const int xlu = (int)floorf(ixc - hx);        // unclamped
        const int xhu = (int)floorf(ixc + hx) + 1;
        const int ylu = (int)floorf(iyc - hy);
        const int yhu = (int)floorf(iyc + hy) + 1;
        const bool interior = (xlu >= 1) & (xhu <= IMW - 2) &
                              (ylu >= 1) & (yhu <= IMH - 2);

        const int x_lo = min(max(xlu, 0), IMW - 1);
        const int x_hi = min(max(xhu, 0), IMW - 1);
        const int y_lo = min(max(ylu, 0), IMH - 1);
        const int y_hi = min(max(yhu, 0), IMH - 1);
        const int xs  = (x_lo - 1) & ~1;   // even staging origin (may be -2)
        const int ys  = y_lo - 1;          // staging origin      (may be -1)
        const int ncs = x_hi + 2 - xs;     // staged cols
        const int nrs = y_hi + 2 - ys;     // staged rows
        const bool fits = (ncs <= NC_MAX) & (nrs <= BH_T);

        // --- per-thread sample coords: 2 px stacked in h --------------------
        const int hq = h0h + hoff;
        const float ixa = Cx + a00 * (float)wq + a01 * (float)hq;
        const float iya = Cy + a10 * (float)wq + a11 * (float)hq;
        const float ixb = ixa + a01;
        const float iyb = iya + a11;

        const float x0fa = floorf(ixa), y0fa = floorf(iya);
        const float x0fb = floorf(ixb), y0fb = floorf(iyb);
        const float wx1a = ixa - x0fa, wy1a = iya - y0fa;
        const float wx1b = ixb - x0fb, wy1b = iyb - y0fb;
        const float wx0a = 1.0f - wx1a, wy0a = 1.0f - wy1a;
        const float wx0b = 1.0f - wx1b, wy0b = 1.0f - wy1b;

        float w00a, w10a, w01a, w11a, w00b, w10b, w01b, w11b;
        if (interior) {                     // block-uniform branch
            w00a = wx0a * wy0a; w10a = wx1a * wy0a;
            w01a = wx0a * wy1a; w11a = wx1a * wy1a;
            w00b = wx0b * wy0b; w10b = wx1b * wy0b;
            w01b = wx0b * wy1b; w11b = wx1b * wy1b;
        } else {
            const bool vx0a = (x0fa >= 0.0f) & (x0fa <= (float)(IMW - 1));
            const bool vx1a = (x0fa >= -1.0f) & (x0fa <= (float)(IMW - 2));
            const bool vy0a = (y0fa >= 0.0f) & (y0fa <= (float)(IMH - 1));
            const bool vy1a = (y0fa >= -1.0f) & (y0fa <= (float)(IMH - 2));
            w00a = (vx0a && vy0a) ? (wx0a * wy0a) : 0.0f;
            w10a = (vx1a && vy0a) ? (wx1a * wy0a) : 0.0f;
            w01a = (vx0a && vy1a) ? (wx0a * wy1a) : 0.0f;
            w11a = (vx1a && vy1a) ? (wx1a * wy1a) : 0.0f;
            const bool vx0b = (x0fb >= 0.0f) & (x0fb <= (float)(IMW - 1));
            const bool vx1b = (x0fb >= -1.0f) & (x0fb <= (float)(IMW - 2));
            const bool vy0b = (y0fb >= 0.0f) & (y0fb <= (float)(IMH - 1));
            const bool vy1b = (y0fb >= -1.0f) & (y0fb <= (float)(IMH - 2));
            w00b = (vx0b && vy0b) ? (wx0b * wy0b) : 0.0f;
            w10b = (vx1b && vy0b) ? (wx1b * wy0b) : 0.0f;
            w01b = (vx0b && vy1b) ? (wx0b * wy1b) : 0.0f;
            w11b = (vx1b && vy1b) ? (wx1b * wy1b) : 0.0f;
        }

        const int x0ia = (int)x0fa, y0ia = (int)y0fa;
        const int x0ib = (int)x0fb, y0ib = (int)y0fb;
        const int obase = (b * CHAN) * plane + hq * IMW + wq;

        // protect LDS reuse from the previous half's reads
        if (half) __syncthreads();

        if (fits) {
            // Stager: 32 float2-lanes x 8 rows per round; packed-RGB writes,
            // one LDS base per (round,thread), 6 stores at offsets 0..5.
            // No zero-fill: clamped addresses; any tap that could read a
            // garbage cell has weight exactly 0 (reference semantics).
            const int nrd = (nrs + 7) >> 3;           // 1..6 row rounds
            const bool wcol = lx2 < ncs;
            const int xg = min(max(xs + lx2, 0), IMW - 2);   // even
            for (int rr = 0; rr < nrd; ++rr) {
                const int dy = (rr << 3) + lyr;
                if (wcol & (dy < nrs)) {
                    const int yg = min(max(ys + dy, 0), IMH - 1);
                    const float* src = ibase + yg * IMW + xg;
                    const float2 v0 = *(const float2*)(src);
                    const float2 v1 = *(const float2*)(src + plane);
                    const float2 v2 = *(const float2*)(src + 2 * plane);
                    float* dst = &tile[dy * ROWSTR + lx2 * 3];
                    dst[0] = v0.x; dst[1] = v1.x; dst[2] = v2.x;
                    dst[3] = v0.y; dst[4] = v1.y; dst[5] = v2.y;
                }
            }
        }
        __syncthreads();

        if (fits) {
            // Gather from LDS. Interior: unclamped (halo + bbox proof).
            // Border: clamp into written region (no uninitialized reads).
            int rxa, rya, rxb, ryb;
            if (interior) {
                rxa = x0ia - xs;  rya = y0ia - ys;
                rxb = x0ib - xs;  ryb = y0ib - ys;
            } else {
                rxa = min(max(x0ia - xs, 0), ncs - 2);
                rya = min(max(y0ia - ys, 0), nrs - 2);
                rxb = min(max(x0ib - xs, 0), ncs - 2);
                ryb = min(max(y0ib - ys, 0), nrs - 2);
            }
            const float* tpa = &tile[rya * ROWSTR + rxa * 3];
            const float* tpb = &tile[ryb * ROWSTR + rxb * 3];
#pragma unroll
            for (int cc = 0; cc < CHAN; ++cc) {
                const float va = w00a * tpa[cc]          + w10a * tpa[cc + 3]
                               + w01a * tpa[cc + ROWSTR] + w11a * tpa[cc + ROWSTR + 3];
                const float vb = w00b * tpb[cc]          + w10b * tpb[cc + 3]
                               + w01b * tpb[cc + ROWSTR] + w11b * tpb[cc + ROWSTR + 3];
                out[obase + cc * plane]       = va;
                out[obase + cc * plane + IMW] = vb;
            }
        } else {
            // fallback: direct global gathers (extreme rotation/shear tail)
            const int x0ca = min(max(x0ia, 0), IMW - 1);
            const int x1ca = min(max(x0ia + 1, 0), IMW - 1);
            const int y0ca = min(max(y0ia, 0), IMH - 1);
            const int y1ca = min(max(y0ia + 1, 0), IMH - 1);
            const int x0cb = min(max(x0ib, 0), IMW - 1);
            const int x1cb = min(max(x0ib + 1, 0), IMW - 1);
            const int y0cb = min(max(y0ib, 0), IMH - 1);
            const int y1cb = min(max(y0ib + 1, 0), IMH - 1);
#pragma unroll
            for (int cc = 0; cc < CHAN; ++cc) {
                const float* p2 = ibase + cc * plane;
                const float va = w00a * p2[y0ca * IMW + x0ca] + w10a * p2[y0ca * IMW + x1ca]
                               + w01a * p2[y1ca * IMW + x0ca] + w11a * p2[y1ca * IMW + x1ca];
                const float vb = w00b * p2[y0cb * IMW + x0cb] + w10b * p2[y0cb * IMW + x1cb]
                               + w01b * p2[y1cb * IMW + x0cb] + w11b * p2[y1cb * IMW + x1cb];
                out[obase + cc * plane]       = va;
                out[obase + cc * plane + IMW] = vb;
            }
        }
    }
}

extern "C" void kernel_launch(void* const* d_in, const int* in_sizes, int n_in,
                              void* d_out, int out_size, void* d_ws, size_t ws_size,
                              hipStream_t stream) {
    const float* img   = (const float*)d_in[0];
    const float* rot   = (const float*)d_in[1];
    const float* trans = (const float*)d_in[2];
    const float* scale = (const float*)d_in[3];
    const float* shear = (const float*)d_in[4];
    float* out = (float*)d_out;

    const int nblocks = BATCH * 64;   // 8192 blocks, 2 half-tiles each
    affine_sample_kernel<<<nblocks, 256, 0, stream>>>(img, rot, trans, scale,
                                                      shear, out);
}

// Round 12
// 41.440 us; speedup vs baseline: 1.0465x; 1.0465x over previous
//
#include <hip/hip_runtime.h>
#include <math.h>

// Problem constants (from reference): B=128, C=3, H=256, W=256, fp32.
#define BATCH 128
#define CHAN  3
#define IMH   256
#define IMW   256
#define NXCD  8
#define TW    32   // output tile width  (per block)
#define TH    16   // output tile height (per block) -- 2 px per thread in h

// Packed-RGB LDS tile: [row][col*3 + ch]. 42 rows x 44 cols x 3 ch.
// Row stride 132 dwords; 42*132*4 = 22,176 B -> 7 blocks/CU.
// One base address serves all 6 tap-pairs of a pixel (read2 offsets
// (cc,cc+3) and (cc+132,cc+135), all < 255 dwords) and all 6 stager writes.
#define BH_T   42
#define NC_MAX 44
#define ROWSTR 132   // NC_MAX * 3

// ---------------------------------------------------------------------------
// Single fused kernel. Block = 256 threads = one 32x16 output tile, 2 px per
// thread stacked in h (R10 structure -- best measured). Packed-RGB LDS (R11's
// conflict win: 6.3M -> 4.1M). Stager is 2-deep software-pipelined: round
// rr+1's global loads issue BEFORE round rr's LDS writes, hiding the ~400cy
// L2/HBM latency under the write+addr work (T14 issue-early/write-late).
// ---------------------------------------------------------------------------
__global__ __launch_bounds__(256) void affine_sample_kernel(
        const float* __restrict__ img,
        const float* __restrict__ rot,
        const float* __restrict__ trans,
        const float* __restrict__ scale,
        const float* __restrict__ shear,
        float* __restrict__ out) {
    __shared__ float tile[BH_T * ROWSTR];   // 22,176 B

    const int NBLK = BATCH * (IMH / TH) * (IMW / TW);   // 128*16*8 = 16384
    const int p = blockIdx.x;
    const int L = (p & (NXCD - 1)) * (NBLK / NXCD) + (p >> 3);  // XCD-chunked

    const int b  = L >> 7;            // 128 tiles per image
    const int tl = L & 127;
    const int w0 = (tl & 7) * TW;
    const int h0 = (tl >> 3) * TH;

    // --- per-image params, block-uniform; HW trig --------------------------
    const float r   = rot[b];
    const float s   = scale[b];
    const float shx = shear[2 * b + 0];
    const float shy = shear[2 * b + 1];
    const float txr = trans[2 * b + 0];
    const float tyr = trans[2 * b + 1];
    const float c  = __cosf(r);       // v_cos_f32 (~1e-6 abs err vs 2e-2 tol)
    const float sn = __sinf(r);
    const float a00 = s * (c - sn * shy);
    const float a01 = s * (c * shx - sn);
    const float a10 = s * (sn + c * shy);
    const float a11 = s * (sn * shx + c);
    // linearized: ix(w,h) = Cx + a00*w + a01*h (exact; map is affine in w,h)
    const float g0x = 1.0f / (float)IMW - 1.0f;   // gx at w=0
    const float g0y = 1.0f / (float)IMH - 1.0f;   // gy at h=0
    const float Cx = ((a00 * g0x + a01 * g0y + txr + 1.0f) * (float)IMW - 1.0f) * 0.5f;
    const float Cy = ((a10 * g0x + a11 * g0y + tyr + 1.0f) * (float)IMH - 1.0f) * 0.5f;
    const float hx = 15.5f * fabsf(a00) + 7.5f * fabsf(a01);
    const float hy = 15.5f * fabsf(a10) + 7.5f * fabsf(a11);

    // --- block-uniform bbox of the input footprint -------------------------
    const float ixc = Cx + a00 * ((float)w0 + 15.5f) + a01 * ((float)h0 + 7.5f);
    const float iyc = Cy + a10 * ((float)w0 + 15.5f) + a11 * ((float)h0 + 7.5f);
    const int xlu = (int)floorf(ixc - hx);        // unclamped
    const int xhu = (int)floorf(ixc + hx) + 1;
    const int ylu = (int)floorf(iyc - hy);
    const int yhu = (int)floorf(iyc + hy) + 1;
    // all 4 taps of every pixel provably in-range
    const bool interior = (xlu >= 1) & (xhu <= IMW - 2) & (ylu >= 1) & (yhu <= IMH - 2);

    const int x_lo = min(max(xlu, 0), IMW - 1);
    const int x_hi = min(max(xhu, 0), IMW - 1);
    const int y_lo = min(max(ylu, 0), IMH - 1);
    const int y_hi = min(max(yhu, 0), IMH - 1);
    const int xs  = (x_lo - 1) & ~1;   // even staging origin (may be -2)
    const int ys  = y_lo - 1;          // staging origin      (may be -1)
    const int ncs = x_hi + 2 - xs;     // staged cols
    const int nrs = y_hi + 2 - ys;     // staged rows

    // --- per-thread sample coords: 2 px stacked in h -----------------------
    const int t  = threadIdx.x;
    const int wq = w0 + (t & 31);
    const int hq = h0 + ((t >> 5) << 1);          // even row; px at hq, hq+1
    const float ixa = Cx + a00 * (float)wq + a01 * (float)hq;
    const float iya = Cy + a10 * (float)wq + a11 * (float)hq;
    const float ixb = ixa + a01;
    const float iyb = iya + a11;

    const float x0fa = floorf(ixa), y0fa = floorf(iya);
    const float x0fb = floorf(ixb), y0fb = floorf(iyb);
    const float wx1a = ixa - x0fa, wy1a = iya - y0fa;
    const float wx1b = ixb - x0fb, wy1b = iyb - y0fb;
    const float wx0a = 1.0f - wx1a, wy0a = 1.0f - wy1a;
    const float wx0b = 1.0f - wx1b, wy0b = 1.0f - wy1b;

    float w00a, w10a, w01a, w11a, w00b, w10b, w01b, w11b;
    if (interior) {                     // block-uniform branch
        w00a = wx0a * wy0a; w10a = wx1a * wy0a;
        w01a = wx0a * wy1a; w11a = wx1a * wy1a;
        w00b = wx0b * wy0b; w10b = wx1b * wy0b;
        w01b = wx0b * wy1b; w11b = wx1b * wy1b;
    } else {
        const bool vx0a = (x0fa >= 0.0f) & (x0fa <= (float)(IMW - 1));
        const bool vx1a = (x0fa >= -1.0f) & (x0fa <= (float)(IMW - 2));
        const bool vy0a = (y0fa >= 0.0f) & (y0fa <= (float)(IMH - 1));
        const bool vy1a = (y0fa >= -1.0f) & (y0fa <= (float)(IMH - 2));
        w00a = (vx0a && vy0a) ? (wx0a * wy0a) : 0.0f;
        w10a = (vx1a && vy0a) ? (wx1a * wy0a) : 0.0f;
        w01a = (vx0a && vy1a) ? (wx0a * wy1a) : 0.0f;
        w11a = (vx1a && vy1a) ? (wx1a * wy1a) : 0.0f;
        const bool vx0b = (x0fb >= 0.0f) & (x0fb <= (float)(IMW - 1));
        const bool vx1b = (x0fb >= -1.0f) & (x0fb <= (float)(IMW - 2));
        const bool vy0b = (y0fb >= 0.0f) & (y0fb <= (float)(IMH - 1));
        const bool vy1b = (y0fb >= -1.0f) & (y0fb <= (float)(IMH - 2));
        w00b = (vx0b && vy0b) ? (wx0b * wy0b) : 0.0f;
        w10b = (vx1b && vy0b) ? (wx1b * wy0b) : 0.0f;
        w01b = (vx0b && vy1b) ? (wx0b * wy1b) : 0.0f;
        w11b = (vx1b && vy1b) ? (wx1b * wy1b) : 0.0f;
    }

    const int x0ia = (int)x0fa, y0ia = (int)y0fa;
    const int x0ib = (int)x0fb, y0ib = (int)y0fb;

    const int plane = IMH * IMW;
    const int obase = (b * CHAN) * plane + hq * IMW + wq;
    const float* ibase = img + (size_t)(b * CHAN) * plane;

    // --- staged path iff footprint fits LDS. Block-uniform branch. ---------
    if (ncs <= NC_MAX && nrs <= BH_T) {
        // Stager: 32 float2-lanes (64 cols) x 8 rows per round; 2-deep
        // software pipeline: round rr+1's loads issue before round rr's
        // LDS writes. No zero-fill: clamped addresses; any tap that could
        // read a garbage cell has weight exactly 0 (reference semantics).
        const int lx2 = (t & 31) << 1;            // 0,2,..,62
        const int lyr = t >> 5;                   // 0..7
        const int nrd = (nrs + 7) >> 3;           // 1..6 row rounds
        const bool wcol = lx2 < ncs;
        const int xg = min(max(xs + lx2, 0), IMW - 2);   // even

        float2 v0, v1, v2;                        // in-flight round
        {   // prologue: load round 0
            const int dy = lyr;
            const int yg = min(max(ys + dy, 0), IMH - 1);
            const float* src = ibase + yg * IMW + xg;
            if (wcol) { v0 = *(const float2*)(src);
                        v1 = *(const float2*)(src + plane);
                        v2 = *(const float2*)(src + 2 * plane); }
        }
        for (int rr = 0; rr < nrd; ++rr) {
            const int dy = (rr << 3) + lyr;
            float2 n0, n1, n2;                    // prefetch round rr+1
            const int dyn = dy + 8;
            if ((rr + 1 < nrd) & wcol & (dyn < nrs)) {
                const int yg = min(max(ys + dyn, 0), IMH - 1);
                const float* src = ibase + yg * IMW + xg;
                n0 = *(const float2*)(src);
                n1 = *(const float2*)(src + plane);
                n2 = *(const float2*)(src + 2 * plane);
            }
            if (wcol & (dy < nrs)) {              // write round rr
                float* dst = &tile[dy * ROWSTR + lx2 * 3];
                dst[0] = v0.x; dst[1] = v1.x; dst[2] = v2.x;
                dst[3] = v0.y; dst[4] = v1.y; dst[5] = v2.y;
            }
            v0 = n0; v1 = n1; v2 = n2;
        }
        __syncthreads();

        // Gather from LDS. Interior: unclamped (halo + bbox proof covers it).
        // Border: clamp into written region (no uninitialized reads).
        int rxa, rya, rxb, ryb;
        if (interior) {
            rxa = x0ia - xs;  rya = y0ia - ys;
            rxb = x0ib - xs;  ryb = y0ib - ys;
        } else {
            rxa = min(max(x0ia - xs, 0), ncs - 2);
            rya = min(max(y0ia - ys, 0), nrs - 2);
            rxb = min(max(x0ib - xs, 0), ncs - 2);
            ryb = min(max(y0ib - ys, 0), nrs - 2);
        }
        const float* tpa = &tile[rya * ROWSTR + rxa * 3];
        const float* tpb = &tile[ryb * ROWSTR + rxb * 3];
#pragma unroll
        for (int cc = 0; cc < CHAN; ++cc) {
            const float va = w00a * tpa[cc]          + w10a * tpa[cc + 3]
                           + w01a * tpa[cc + ROWSTR] + w11a * tpa[cc + ROWSTR + 3];
            const float vb = w00b * tpb[cc]          + w10b * tpb[cc + 3]
                           + w01b * tpb[cc + ROWSTR] + w11b * tpb[cc + ROWSTR + 3];
            out[obase + cc * plane]       = va;
            out[obase + cc * plane + IMW] = vb;
        }
    } else {
        // fallback: direct global gathers (extreme rotation/shear tail only)
        const int x0ca = min(max(x0ia, 0), IMW - 1);
        const int x1ca = min(max(x0ia + 1, 0), IMW - 1);
        const int y0ca = min(max(y0ia, 0), IMH - 1);
        const int y1ca = min(max(y0ia + 1, 0), IMH - 1);
        const int x0cb = min(max(x0ib, 0), IMW - 1);
        const int x1cb = min(max(x0ib + 1, 0), IMW - 1);
        const int y0cb = min(max(y0ib, 0), IMH - 1);
        const int y1cb = min(max(y0ib + 1, 0), IMH - 1);
#pragma unroll
        for (int cc = 0; cc < CHAN; ++cc) {
            const float* p2 = ibase + cc * plane;
            const float va = w00a * p2[y0ca * IMW + x0ca] + w10a * p2[y0ca * IMW + x1ca]
                           + w01a * p2[y1ca * IMW + x0ca] + w11a * p2[y1ca * IMW + x1ca];
            const float vb = w00b * p2[y0cb * IMW + x0cb] + w10b * p2[y0cb * IMW + x1cb]
                           + w01b * p2[y1cb * IMW + x0cb] + w11b * p2[y1cb * IMW + x1cb];
            out[obase + cc * plane]       = va;
            out[obase + cc * plane + IMW] = vb;
        }
    }
}

extern "C" void kernel_launch(void* const* d_in, const int* in_sizes, int n_in,
                              void* d_out, int out_size, void* d_ws, size_t ws_size,
                              hipStream_t stream) {
    const float* img   = (const float*)d_in[0];
    const float* rot   = (const float*)d_in[1];
    const float* trans = (const float*)d_in[2];
    const float* scale = (const float*)d_in[3];
    const float* shear = (const float*)d_in[4];
    float* out = (float*)d_out;

    const int nblocks = BATCH * (IMH / TH) * (IMW / TW);   // 16384
    affine_sample_kernel<<<nblocks, 256, 0, stream>>>(img, rot, trans, scale,
                                                      shear, out);
}